// Round 5
// baseline (1094.782 us; speedup 1.0000x reference)
//
#include <hip/hip_runtime.h>

#define TT 512

typedef float f32x2 __attribute__((ext_vector_type(2)));
typedef float f32x4 __attribute__((ext_vector_type(4)));

template<int CTRL>
__device__ __forceinline__ float dpp_mov(float v) {
    return __int_as_float(__builtin_amdgcn_mov_dpp(__float_as_int(v), CTRL, 0xF, 0xF, true));
}
__device__ __forceinline__ float swz_xor4(float v) {
    return __int_as_float(__builtin_amdgcn_ds_swizzle(__float_as_int(v), 0x101F));
}
__device__ __forceinline__ float swz_xor8(float v) {
    return __int_as_float(__builtin_amdgcn_ds_swizzle(__float_as_int(v), 0x201F));
}
// packed fp32 FMA/MUL, forced
__device__ __forceinline__ void pk(f32x2& a, f32x2 w, f32x2 v) {
    asm("v_pk_fma_f32 %0, %1, %2, %0" : "+v"(a) : "v"(w), "v"(v));
}
__device__ __forceinline__ f32x2 pkmul(f32x2 w, f32x2 v) {
    f32x2 a;
    asm("v_pk_mul_f32 %0, %1, %2" : "=v"(a) : "v"(w), "v"(v));
    return a;
}

// Select-free xor-merge; lane q holds slot-permuted partials (slot s ->
// output s ^ p(q), p = 4q0+2q1+q2), so every level is uniformly
// s[i] += perm(s[i+H]) with zero cndmasks.
__device__ __forceinline__ float merge8(float* s) {      // 3 levels (8 lanes)
    s[0] += dpp_mov<0xB1>(s[4]);
    s[1] += dpp_mov<0xB1>(s[5]);
    s[2] += dpp_mov<0xB1>(s[6]);
    s[3] += dpp_mov<0xB1>(s[7]);
    s[0] += dpp_mov<0x4E>(s[2]);
    s[1] += dpp_mov<0x4E>(s[3]);
    return s[0] + swz_xor4(s[1]);
}
__device__ __forceinline__ float merge16(float* s) {     // 4 levels (16 lanes)
    float r = merge8(s);
    return r + swz_xor8(r);                              // k-half partner
}

// ---------------------------------------------------------------------------
// Decoder: 256 blocks x 1024 threads, 2 batch rows/block.
// tid = gg*8 + q; gg = j in [0,128), q in [0,8) = k-slice id (16 floats).
// Weights: 4 gate-rows x 16k = 16 f32x4 = 64 VGPRs, arch-resident
// (amdgpu_waves_per_eu(4,4) grants the full 128-reg budget; grid is
// 1 block/CU anyway so higher occupancy is impossible).
// ---------------------------------------------------------------------------
__global__ __launch_bounds__(1024)
__attribute__((amdgpu_waves_per_eu(4, 4)))
void dec_kernel(const float* __restrict__ h_enc,  // [B,64]
                const float* __restrict__ Wih,    // [512,64]
                const float* __restrict__ Whh,    // [512,128]
                const float* __restrict__ bias,   // [512]
                float* __restrict__ out)          // [B,T,128]
{
    const int tid = threadIdx.x;
    const int gg  = tid >> 3;               // j
    const int q   = tid & 7;
    const int q0 = q & 1, q1 = (q >> 1) & 1, q2 = (q >> 2) & 1;
    const int msk2 = (q0 << 1) | q1;
    const int b0  = blockIdx.x * 2;

    __shared__ __align__(16) float he[2][64];
    __shared__ __align__(16) float hb[2][2 * 160];   // [buf][row*160 + padded j]

    if (tid < 128) he[tid >> 6][tid & 63] = h_enc[(size_t)(b0 + (tid >> 6)) * 64 + (tid & 63)];
    if (tid < 256) {
        int r = tid >> 7, j = tid & 127;
        hb[0][r * 160 + j + 4 * (j >> 4)] = 0.f;
    }

    // recurrent weights -> registers (slot-permuted rows: m ^ msk2)
    f32x4 w[4][4];
    #pragma unroll
    for (int m = 0; m < 4; ++m) {
        const float* src = Whh + (size_t)((m ^ msk2) * 128 + gg) * 128 + 16 * q;
        #pragma unroll
        for (int c = 0; c < 4; ++c) w[m][c] = *(const f32x4*)(src + 4 * c);
    }

    const int t4own = 2 * q0 + q1;
    const float sA = (t4own == 2) ? 2.f : 1.f;
    const float sC = (t4own == 2) ? -1.f : 0.f;
    const bool writer = (q0 == 0) && (q1 == 0);
    const int rr  = q2;
    const int oA  = q2 * 160;
    const int oB  = (q2 ^ 1) * 160;
    const int kres = 20 * q;
    const int pwj = q2 * 160 + gg + 4 * (gg >> 4);

    __syncthreads();

    // xp = bias + Wih_d . h_enc (time-invariant; same permuted merge layout)
    float xp;
    {
        const float* heA = he[q2] + 8 * q;
        const float* heB = he[q2 ^ 1] + 8 * q;
        f32x4 hA0 = *(const f32x4*)heA, hA1 = *(const f32x4*)(heA + 4);
        f32x4 hB0 = *(const f32x4*)heB, hB1 = *(const f32x4*)(heB + 4);
        float s[8];
        #pragma unroll
        for (int m = 0; m < 4; ++m) {
            const float* ws = Wih + (size_t)((m ^ msk2) * 128 + gg) * 64 + 8 * q;
            f32x4 w0 = *(const f32x4*)ws, w1 = *(const f32x4*)(ws + 4);
            f32x2 aA = pkmul(w0.lo, hA0.lo);
            pk(aA, w0.hi, hA0.hi); pk(aA, w1.lo, hA1.lo); pk(aA, w1.hi, hA1.hi);
            f32x2 aB = pkmul(w0.lo, hB0.lo);
            pk(aB, w0.hi, hB0.hi); pk(aB, w1.lo, hB1.lo); pk(aB, w1.hi, hB1.hi);
            s[2 * m]     = aA.x + aA.y;
            s[2 * m + 1] = aB.x + aB.y;
        }
        xp = merge8(s) + bias[t4own * 128 + gg];
    }

    float c_state = 0.f;
    size_t optr = ((size_t)(b0 + rr) * TT) * 128 + gg;

#define DSTEP(CUR, NXT) {                                                      \
    const float* bAp = (CUR) + oA + kres;                                      \
    const float* bBp = (CUR) + oB + kres;                                      \
    f32x4 ch[4]; f32x2 accA[4], accB[4];                                       \
    _Pragma("unroll") for (int c = 0; c < 4; ++c) ch[c] = *(const f32x4*)(bAp + 4 * c); \
    _Pragma("unroll") for (int m = 0; m < 4; ++m) { f32x2 z2 = pkmul(w[m][0].lo, ch[0].lo); \
        pk(z2, w[m][0].hi, ch[0].hi);                                          \
        _Pragma("unroll") for (int c = 1; c < 4; ++c) { pk(z2, w[m][c].lo, ch[c].lo); pk(z2, w[m][c].hi, ch[c].hi); } \
        accA[m] = z2; }                                                        \
    _Pragma("unroll") for (int c = 0; c < 4; ++c) ch[c] = *(const f32x4*)(bBp + 4 * c); \
    _Pragma("unroll") for (int m = 0; m < 4; ++m) { f32x2 z2 = pkmul(w[m][0].lo, ch[0].lo); \
        pk(z2, w[m][0].hi, ch[0].hi);                                          \
        _Pragma("unroll") for (int c = 1; c < 4; ++c) { pk(z2, w[m][c].lo, ch[c].lo); pk(z2, w[m][c].hi, ch[c].hi); } \
        accB[m] = z2; }                                                        \
    float s[8];                                                                \
    _Pragma("unroll") for (int m = 0; m < 4; ++m) {                            \
        s[2 * m] = accA[m].x + accA[m].y; s[2 * m + 1] = accB[m].x + accB[m].y; } \
    float z = merge8(s) + xp;                                                  \
    float ez = __expf(-z * sA);                                                \
    float v  = fmaf(__builtin_amdgcn_rcpf(1.0f + ez), sA, sC);                 \
    float vi = dpp_mov<0x00>(v); float vg = dpp_mov<0x55>(v);                  \
    float vf = dpp_mov<0xAA>(v); float vo = dpp_mov<0xFF>(v);                  \
    c_state = fmaf(vf, c_state, vi * vg);                                      \
    float e2 = __expf(-2.f * c_state);                                         \
    float hv = vo * fmaf(__builtin_amdgcn_rcpf(1.f + e2), 2.f, -1.f);          \
    if (writer) { (NXT)[pwj] = hv; out[optr] = hv; }                           \
    optr += 128;                                                               \
    __syncthreads(); }

    #pragma unroll 1
    for (int t = 0; t < TT; t += 2) {
        DSTEP(hb[0], hb[1]);
        DSTEP(hb[1], hb[0]);
    }
#undef DSTEP
}

// ---------------------------------------------------------------------------
// Encoder: 256 blocks x 1024 threads, 2 batch rows/block.
// tid = gg*16 + q; gg = j in [0,64), q in [0,16).
// q0,q1 -> gate-type perm, q2 -> batch-row perm, q3 -> k-half (free merge
// level). Thread: 4 gate-rows x 12k slice of concat [x(128)|h(64)] = 192.
// Weights: 12 f32x4 = 48 VGPRs. 48 pk_fma + 6 ds_read_b128 per step.
// ---------------------------------------------------------------------------
__global__ __launch_bounds__(1024)
__attribute__((amdgpu_waves_per_eu(4, 4)))
void enc_kernel(const float* __restrict__ x,      // [B,T,128]
                const float* __restrict__ Wih,    // [256,128]
                const float* __restrict__ Whh,    // [256,64]
                const float* __restrict__ bias,   // [256]
                float* __restrict__ h_out)        // [B,64]
{
    const int tid = threadIdx.x;
    const int gg  = tid >> 4;               // j in [0,64)
    const int q   = tid & 15;
    const int q0 = q & 1, q1 = (q >> 1) & 1, q2 = (q >> 2) & 1;
    const int msk2 = (q0 << 1) | q1;
    const int b0  = blockIdx.x * 2;

    __shared__ __align__(16) float xh[2][2 * 192];  // [buf][row*192 + k]

    f32x4 w[4][3];
    #pragma unroll
    for (int m = 0; m < 4; ++m) {
        int row = (m ^ msk2) * 64 + gg;
        #pragma unroll
        for (int c = 0; c < 3; ++c) {
            int k0 = 12 * q + 4 * c;
            const float* src = (k0 < 128) ? (Wih + (size_t)row * 128 + k0)
                                          : (Whh + (size_t)row * 64 + (k0 - 128));
            w[m][c] = *(const f32x4*)src;
        }
    }

    const int t4own = 2 * q0 + q1;
    const float sA = (t4own == 2) ? 2.f : 1.f;
    const float sC = (t4own == 2) ? -1.f : 0.f;
    const bool writer = (q0 == 0) && (q1 == 0) && (((q >> 3) & 1) == 0); // q in {0,4}
    const int oA  = q2 * 192;
    const int oB  = (q2 ^ 1) * 192;
    const int kres = 12 * q;
    const int pwj = q2 * 192 + 128 + gg;
    const float xpc = bias[t4own * 64 + gg];

    const bool stager = (tid < 64);
    const int sr = (tid >> 5) & 1, sc = tid & 31;
    const int psl = sr * 192 + 4 * sc;
    const float* xbase = x + ((size_t)(b0 + sr) * TT) * 128 + 4 * sc;

    if (stager) *(f32x4*)(&xh[0][psl]) = *(const f32x4*)xbase;
    if (tid < 128) xh[0][(tid >> 6) * 192 + 128 + (tid & 63)] = 0.f;

    float c_state = 0.f;
    float h_last = 0.f;
    __syncthreads();

#define ESTEP(CUR, NXT, T) {                                                   \
    f32x4 xnext;                                                               \
    if (stager) { int tl = (T) + 1 < TT ? (T) + 1 : TT - 1;                    \
        xnext = *(const f32x4*)(xbase + (size_t)tl * 128); }                   \
    const float* bAp = (CUR) + oA + kres;                                      \
    const float* bBp = (CUR) + oB + kres;                                      \
    f32x4 ch[3]; f32x2 accA[4], accB[4];                                       \
    _Pragma("unroll") for (int c = 0; c < 3; ++c) ch[c] = *(const f32x4*)(bAp + 4 * c); \
    _Pragma("unroll") for (int m = 0; m < 4; ++m) { f32x2 z2 = pkmul(w[m][0].lo, ch[0].lo); \
        pk(z2, w[m][0].hi, ch[0].hi);                                          \
        pk(z2, w[m][1].lo, ch[1].lo); pk(z2, w[m][1].hi, ch[1].hi);            \
        pk(z2, w[m][2].lo, ch[2].lo); pk(z2, w[m][2].hi, ch[2].hi);            \
        accA[m] = z2; }                                                        \
    _Pragma("unroll") for (int c = 0; c < 3; ++c) ch[c] = *(const f32x4*)(bBp + 4 * c); \
    _Pragma("unroll") for (int m = 0; m < 4; ++m) { f32x2 z2 = pkmul(w[m][0].lo, ch[0].lo); \
        pk(z2, w[m][0].hi, ch[0].hi);                                          \
        pk(z2, w[m][1].lo, ch[1].lo); pk(z2, w[m][1].hi, ch[1].hi);            \
        pk(z2, w[m][2].lo, ch[2].lo); pk(z2, w[m][2].hi, ch[2].hi);            \
        accB[m] = z2; }                                                        \
    float s[8];                                                                \
    _Pragma("unroll") for (int m = 0; m < 4; ++m) {                            \
        s[2 * m] = accA[m].x + accA[m].y; s[2 * m + 1] = accB[m].x + accB[m].y; } \
    float z = merge16(s) + xpc;                                                \
    float ez = __expf(-z * sA);                                                \
    float v  = fmaf(__builtin_amdgcn_rcpf(1.0f + ez), sA, sC);                 \
    float vi = dpp_mov<0x00>(v); float vg = dpp_mov<0x55>(v);                  \
    float vf = dpp_mov<0xAA>(v); float vo = dpp_mov<0xFF>(v);                  \
    c_state = fmaf(vf, c_state, vi * vg);                                      \
    float e2 = __expf(-2.f * c_state);                                         \
    float hv = vo * fmaf(__builtin_amdgcn_rcpf(1.f + e2), 2.f, -1.f);          \
    h_last = hv;                                                               \
    if (writer) (NXT)[pwj] = hv;                                               \
    if (stager) *(f32x4*)((NXT) + psl) = xnext;                                \
    __syncthreads(); }

    #pragma unroll 1
    for (int t = 0; t < TT; t += 2) {
        ESTEP(xh[0], xh[1], t);
        ESTEP(xh[1], xh[0], t + 1);
    }
#undef ESTEP

    if (writer) h_out[(size_t)(b0 + q2) * 64 + gg] = h_last;
}

extern "C" void kernel_launch(void* const* d_in, const int* in_sizes, int n_in,
                              void* d_out, int out_size, void* d_ws, size_t ws_size,
                              hipStream_t stream) {
    const float* x     = (const float*)d_in[0];
    const float* Wih_e = (const float*)d_in[1];
    const float* Whh_e = (const float*)d_in[2];
    const float* b_e   = (const float*)d_in[3];
    const float* Wih_d = (const float*)d_in[4];
    const float* Whh_d = (const float*)d_in[5];
    const float* b_d   = (const float*)d_in[6];
    float* out   = (float*)d_out;
    float* h_enc = (float*)d_ws;

    enc_kernel<<<dim3(256), dim3(1024), 0, stream>>>(x, Wih_e, Whh_e, b_e, h_enc);
    dec_kernel<<<dim3(256), dim3(1024), 0, stream>>>(h_enc, Wih_d, Whh_d, b_d, out);
}